// Round 15
// baseline (89.862 us; speedup 1.0000x reference)
//
#include <hip/hip_runtime.h>
#include <hip/hip_bf16.h>

// Sizes (fixed by the problem)
#define NS   4096      // samples
#define NV   256       // variables/channels
#define NHID 64        // hidden
#define K2F  2.8853900817779268f   // 2*log2(e)

typedef short s8v __attribute__((ext_vector_type(8)));
typedef float f4v __attribute__((ext_vector_type(4)));

typedef __attribute__((address_space(1))) const unsigned int GU;
typedef __attribute__((address_space(3))) unsigned int LU;

__device__ __forceinline__ void gload16(const void* gp, void* lp) {
    __builtin_amdgcn_global_load_lds((GU*)gp, (LU*)lp, 16, 0, 0);
}

__device__ __forceinline__ unsigned short f2bf(float x) {
    __hip_bfloat16 h = __float2bfloat16(x);
    return *reinterpret_cast<unsigned short*>(&h);
}

// ---- merged prep: blocks [0,1024): W2t ; [1024,2192): data/out0/g2/BO/bi2 ----
// W2t[col][k] = adj[k,c] * w_in[c, k-(k>c), h],  col = c*64+h
__global__ __launch_bounds__(256) void k_prep_all(
        const float* __restrict__ adj, const float* __restrict__ w_in,
        unsigned short* __restrict__ W2t,
        const float* __restrict__ data, unsigned short* __restrict__ dataB,
        float* __restrict__ out0,
        const float* __restrict__ neurons, const float* __restrict__ w_out,
        const float* __restrict__ b_out, float* __restrict__ g2, float* __restrict__ BO,
        const float* __restrict__ b_in, float* __restrict__ bi2)
{
    __shared__ float t[64][65];
    const int blk = blockIdx.x, tid = threadIdx.x;
    if (blk < 1024) {
        int c  = blk >> 2;
        int k0 = (blk & 3) * 64;
#pragma unroll
        for (int i = 0; i < 16; ++i) {
            int lin = i * 256 + tid;
            int kr = lin >> 6, h = lin & 63;
            int k = k0 + kr;
            float v = 0.0f;
            if (k != c) {
                int m = k - (k > c ? 1 : 0);
                v = adj[k * NV + c] * w_in[((size_t)c * 255 + m) * 64 + h];
            }
            t[kr][h] = v;
        }
        __syncthreads();
#pragma unroll
        for (int i = 0; i < 16; ++i) {
            int lin = i * 256 + tid;
            int h = lin >> 6, kr = lin & 63;
            W2t[((size_t)(c * 64 + h)) * NV + k0 + kr] = f2bf(t[kr][h]);
        }
        return;
    }
    const int b = blk - 1024;
    if (b < 1024) {                       // data f32 -> bf16 (262144 float4)
        int i = b * 256 + tid;
        float4 v = reinterpret_cast<const float4*>(data)[i];
        ushort4 o = make_ushort4(f2bf(v.x), f2bf(v.y), f2bf(v.z), f2bf(v.w));
        reinterpret_cast<ushort4*>(dataB)[i] = o;
    } else if (b < 1088) {                // out0 = adj (16384 float4)
        int i = (b - 1024) * 256 + tid;
        reinterpret_cast<float4*>(out0)[i] = reinterpret_cast<const float4*>(adj)[i];
    } else if (b < 1152) {                // g2[j]=2*neurons[h,c]*w_out[j]; BO[c]=b_out[c]+sum_h g
        int j = (b - 1088) * 256 + tid;
        int c = j >> 6, h = j & 63;
        float gv = neurons[h * NV + c] * w_out[j];
        g2[j] = 2.0f * gv;
        float s = gv;
        s += __shfl_xor(s, 1);  s += __shfl_xor(s, 2);  s += __shfl_xor(s, 4);
        s += __shfl_xor(s, 8);  s += __shfl_xor(s, 16); s += __shfl_xor(s, 32);
        if ((tid & 63) == 0) BO[c] = b_out[c] + s;
    } else {                              // bi2 = K2 * b_in (4096 float4)
        int i = (b - 1152) * 256 + tid;
        float4 v = reinterpret_cast<const float4*>(b_in)[i];
        v.x *= K2F; v.y *= K2F; v.z *= K2F; v.w *= K2F;
        reinterpret_cast<float4*>(bi2)[i] = v;
    }
}

// ---- main: 128x128/BK64/4-wave. A: LDS double-buffered (2x16KB, R8 128B-row
// XOR swizzle, 0 conflicts), staged 1-ahead. B: NEVER in LDS -- JIT global->reg
// b128 loads at top of the SAME iteration (R12-proven addressing; lifetime
// crosses exactly one wait+barrier to dodge the regalloc demotion that killed
// R12/R13's persistent windows). DS-pipe traffic halves (393->195 KB/block);
// B rides the parallel TA/L1 pipe. vmcnt(4) = B(kt)+A(kt) landed, A(kt+1) fly.
// Swapped MFMA (R8): D rows = h, D cols = m; lean exp2 epilogue.
__global__ __launch_bounds__(256, 2) void k_gemm_fused(
        const unsigned short* __restrict__ dataB,   // [4096][256] bf16
        const unsigned short* __restrict__ W2t,     // [16384][256] bf16
        const float* __restrict__ g2,               // [16384] 2*g
        const float* __restrict__ bi2,              // [16384] K2*b_in
        const float* __restrict__ BO,               // [256]  b_out + sum_h g
        float* __restrict__ out1)                   // [4096][256]
{
    __shared__ __align__(16) char lds[32768];       // A buf0 16K | A buf1 16K
    const int tid  = threadIdx.x;
    const int w    = tid >> 6;
    const int lane = tid & 63;
    const int lq   = lane >> 4, lr = lane & 15;
    const int wr   = w >> 1, wc = w & 1;

    // XCD-chunked swizzle (R3/R8-proven): 4096 blocks, 512/XCD.
    const int orig = (int)blockIdx.x;
    const int swz  = (orig & 7) * 512 + (orig >> 3);
    const int bm0  = (swz & 31) << 7;
    const int bn0  = (swz >> 5) << 7;

    f4v acc[4][4];
#pragma unroll
    for (int mi = 0; mi < 4; ++mi)
#pragma unroll
        for (int ni = 0; ni < 4; ++ni)
            acc[mi][ni] = (f4v){0.f, 0.f, 0.f, 0.f};

    // A staging offsets (R8-proven). LDS dest LINEAR; XOR swizzle on GLOBAL
    // source + again on ds_read (rule #21).
    unsigned int offA[4], ldso[4];
#pragma unroll
    for (int t = 0; t < 4; ++t) {
        int o = w * 4096 + t * 1024 + lane * 16;    // byte offset in 16KB A tile
        int row = o >> 7;                            // 128 B per row (64 bf16)
        int inner = (o & 127) ^ ((row & 7) << 4);    // inverse swizzle on source
        ldso[t] = (unsigned)(w * 4096 + t * 1024);   // wave-uniform LDS base
        offA[t] = (unsigned)(bm0 + row) * 512u + (unsigned)inner;
    }
    const char* dA = (const char*)dataB;
    const char* dB = (const char*)W2t;

    // B per-lane base pointers (R12-proven numerics): fragment (ni,kk,kt)
    // lives at pB[ni] + kt*128 + kk*64.
    const char* pB[4];
#pragma unroll
    for (int ni = 0; ni < 4; ++ni)
        pB[ni] = dB + (size_t)(bn0 + wc * 64 + ni * 16 + lr) * 512 + lq * 16;

#define STAGE_A(KT, BUFO)                                                      \
    do {                                                                       \
        _Pragma("unroll")                                                      \
        for (int t = 0; t < 4; ++t)                                            \
            gload16(dA + (size_t)offA[t] + (KT) * 128, lds + (BUFO) + ldso[t]); \
    } while (0)

#define SB __builtin_amdgcn_sched_barrier(0)

    // Prologue: A(0) staged into buf0.
    STAGE_A(0, 0);

#pragma unroll
    for (int kt = 0; kt < 4; ++kt) {
        const int bufo = (kt & 1) << 14;            // 0 / 16384
        // JIT B-frag loads for THIS iteration (consumed below, short-lived).
        s8v bfr0[4], bfr1[4];
        SB;
#pragma unroll
        for (int ni = 0; ni < 4; ++ni) {
            bfr0[ni] = *reinterpret_cast<const s8v*>(pB[ni] + kt * 128);
            bfr1[ni] = *reinterpret_cast<const s8v*>(pB[ni] + kt * 128 + 64);
        }
        SB;
        if (kt < 3) STAGE_A(kt + 1, bufo ^ 16384);
        SB;
        // outstanding: [A(kt) 4 (maybe)], B(kt) 16, A(kt+1) 4 -> leave 4.
        if (kt < 3) { asm volatile("s_waitcnt vmcnt(4)" ::: "memory"); }
        else        { asm volatile("s_waitcnt vmcnt(0)" ::: "memory"); }
        SB; __builtin_amdgcn_s_barrier(); SB;       // A(kt) visible to all waves

#pragma unroll
        for (int kk = 0; kk < 2; ++kk) {
            s8v afr[4];
#pragma unroll
            for (int mi = 0; mi < 4; ++mi) {
                int ml = wr * 64 + mi * 16 + lr;
                int inner = (kk * 64 + (lq << 4)) ^ ((ml & 7) << 4);
                afr[mi] = *reinterpret_cast<const s8v*>(lds + bufo + ml * 128 + inner);
            }
            __builtin_amdgcn_s_setprio(1);
#pragma unroll
            for (int mi = 0; mi < 4; ++mi)
#pragma unroll
                for (int ni = 0; ni < 4; ++ni)
                    acc[mi][ni] = __builtin_amdgcn_mfma_f32_16x16x32_bf16(
                        (kk == 0) ? bfr0[ni] : bfr1[ni], afr[mi],
                        acc[mi][ni], 0, 0, 0);      // SWAPPED: W first
            __builtin_amdgcn_s_setprio(0);
        }

        // end barrier: all waves done reading A buf kt -> safe to restage it.
        SB; __builtin_amdgcn_s_barrier(); SB;
    }
#undef SB
#undef STAGE_A

    // Epilogue (R8-validated): lane holds D[h-local = ni*16+lq*4+j][m-local = lr].
    // out[m,c] = BO[c] - sum_h g2[h] * rcp(1 + exp2(K2*pre + bi2[h]))
    const int cidx = (bn0 >> 6) + wc;               // this wave's channel c
    float4 g2v[4], bi2v[4];
#pragma unroll
    for (int ni = 0; ni < 4; ++ni) {
        int base = cidx * 64 + ni * 16 + lq * 4;
        g2v[ni]  = *(const float4*)&g2 [base];
        bi2v[ni] = *(const float4*)&bi2[base];
    }
    const float BOv = BO[cidx];

    float s0, s1, s2, s3;
#define EPI_TERM(T, GC, BC, RR)                                                \
    { float mm = __builtin_fmaf(acc[mi][ni][RR], K2F, (BC));                   \
      float e  = __builtin_amdgcn_exp2f(mm);                                   \
      (T) = __builtin_fmaf((GC), __builtin_amdgcn_rcpf(e + 1.0f), (T)); }
#define EPI_MI(T)                                                              \
    { float t = 0.f;                                                           \
      _Pragma("unroll")                                                        \
      for (int ni = 0; ni < 4; ++ni) {                                         \
          EPI_TERM(t, g2v[ni].x, bi2v[ni].x, 0);                               \
          EPI_TERM(t, g2v[ni].y, bi2v[ni].y, 1);                               \
          EPI_TERM(t, g2v[ni].z, bi2v[ni].z, 2);                               \
          EPI_TERM(t, g2v[ni].w, bi2v[ni].w, 3);                               \
      }                                                                        \
      t += __shfl_xor(t, 16);                                                  \
      t += __shfl_xor(t, 32);                                                  \
      (T) = t; }
    { const int mi = 0; EPI_MI(s0); }
    { const int mi = 1; EPI_MI(s1); }
    { const int mi = 2; EPI_MI(s2); }
    { const int mi = 3; EPI_MI(s3); }
#undef EPI_MI
#undef EPI_TERM
    float v = lane < 16 ? s0 : (lane < 32 ? s1 : (lane < 48 ? s2 : s3));
    out1[(unsigned)(bm0 + wr * 64 + lane) * NV + cidx] = BOv - v;
}

extern "C" void kernel_launch(void* const* d_in, const int* in_sizes, int n_in,
                              void* d_out, int out_size, void* d_ws, size_t ws_size,
                              hipStream_t stream) {
    const float* data    = (const float*)d_in[0];
    const float* adj     = (const float*)d_in[1];
    const float* neurons = (const float*)d_in[2];
    const float* w_in    = (const float*)d_in[3];
    const float* b_in    = (const float*)d_in[4];
    const float* w_out   = (const float*)d_in[5];
    const float* b_out   = (const float*)d_in[6];

    float* out0 = (float*)d_out;
    float* out1 = out0 + NV * NV;

    unsigned short* dataB = (unsigned short*)d_ws;                       // 2 MiB
    unsigned short* W2t   = (unsigned short*)((char*)d_ws + 2097152);    // 8 MiB
    float*          g2    = (float*)((char*)d_ws + 10485760);            // 64 KiB
    float*          bi2   = (float*)((char*)d_ws + 10551296);            // 64 KiB
    float*          BO    = (float*)((char*)d_ws + 10616832);            // 1 KiB

    hipLaunchKernelGGL(k_prep_all, dim3(2192), dim3(256), 0, stream,
                       adj, w_in, W2t, data, dataB, out0,
                       neurons, w_out, b_out, g2, BO, b_in, bi2);
    hipLaunchKernelGGL(k_gemm_fused, dim3(4096), dim3(256), 0, stream,
                       dataB, W2t, g2, bi2, BO, out1);
}

// Round 16
// 55.725 us; speedup vs baseline: 1.6126x; 1.6126x over previous
//
#include <hip/hip_runtime.h>
#include <hip/hip_bf16.h>

// Sizes (fixed by the problem)
#define NS   4096      // samples
#define NV   256       // variables/channels
#define NHID 64        // hidden
#define K2F  2.8853900817779268f   // 2*log2(e)

typedef short s8v __attribute__((ext_vector_type(8)));
typedef float f4v __attribute__((ext_vector_type(4)));

typedef __attribute__((address_space(1))) const unsigned int GU;
typedef __attribute__((address_space(3))) unsigned int LU;

__device__ __forceinline__ void gload16(const void* gp, void* lp) {
    __builtin_amdgcn_global_load_lds((GU*)gp, (LU*)lp, 16, 0, 0);
}

__device__ __forceinline__ unsigned short f2bf(float x) {
    __hip_bfloat16 h = __float2bfloat16(x);
    return *reinterpret_cast<unsigned short*>(&h);
}

// ---- merged prep: blocks [0,1024): W2t ; [1024,2192): data/out0/g2/BO/bi2 ----
// W2t[col][k] = adj[k,c] * w_in[c, k-(k>c), h],  col = c*64+h
__global__ __launch_bounds__(256) void k_prep_all(
        const float* __restrict__ adj, const float* __restrict__ w_in,
        unsigned short* __restrict__ W2t,
        const float* __restrict__ data, unsigned short* __restrict__ dataB,
        float* __restrict__ out0,
        const float* __restrict__ neurons, const float* __restrict__ w_out,
        const float* __restrict__ b_out, float* __restrict__ g2, float* __restrict__ BO,
        const float* __restrict__ b_in, float* __restrict__ bi2)
{
    __shared__ float t[64][65];
    const int blk = blockIdx.x, tid = threadIdx.x;
    if (blk < 1024) {
        int c  = blk >> 2;
        int k0 = (blk & 3) * 64;
#pragma unroll
        for (int i = 0; i < 16; ++i) {
            int lin = i * 256 + tid;
            int kr = lin >> 6, h = lin & 63;
            int k = k0 + kr;
            float v = 0.0f;
            if (k != c) {
                int m = k - (k > c ? 1 : 0);
                v = adj[k * NV + c] * w_in[((size_t)c * 255 + m) * 64 + h];
            }
            t[kr][h] = v;
        }
        __syncthreads();
#pragma unroll
        for (int i = 0; i < 16; ++i) {
            int lin = i * 256 + tid;
            int h = lin >> 6, kr = lin & 63;
            W2t[((size_t)(c * 64 + h)) * NV + k0 + kr] = f2bf(t[kr][h]);
        }
        return;
    }
    const int b = blk - 1024;
    if (b < 1024) {                       // data f32 -> bf16 (262144 float4)
        int i = b * 256 + tid;
        float4 v = reinterpret_cast<const float4*>(data)[i];
        ushort4 o = make_ushort4(f2bf(v.x), f2bf(v.y), f2bf(v.z), f2bf(v.w));
        reinterpret_cast<ushort4*>(dataB)[i] = o;
    } else if (b < 1088) {                // out0 = adj (16384 float4)
        int i = (b - 1024) * 256 + tid;
        reinterpret_cast<float4*>(out0)[i] = reinterpret_cast<const float4*>(adj)[i];
    } else if (b < 1152) {                // g2[j]=2*neurons[h,c]*w_out[j]; BO[c]=b_out[c]+sum_h g
        int j = (b - 1088) * 256 + tid;
        int c = j >> 6, h = j & 63;
        float gv = neurons[h * NV + c] * w_out[j];
        g2[j] = 2.0f * gv;
        float s = gv;
        s += __shfl_xor(s, 1);  s += __shfl_xor(s, 2);  s += __shfl_xor(s, 4);
        s += __shfl_xor(s, 8);  s += __shfl_xor(s, 16); s += __shfl_xor(s, 32);
        if ((tid & 63) == 0) BO[c] = b_out[c] + s;
    } else {                              // bi2 = K2 * b_in (4096 float4)
        int i = (b - 1152) * 256 + tid;
        float4 v = reinterpret_cast<const float4*>(b_in)[i];
        v.x *= K2F; v.y *= K2F; v.z *= K2F; v.w *= K2F;
        reinterpret_cast<float4*>(bi2)[i] = v;
    }
}

// ---- main: 128x256 tile (M x N), BK=64, 4 waves EACH computing 128x64
// (8 A-frags + 4 B-frags per kk -> 32 MFMA: 0.375 KB/MFMA DS-read vs 0.5 for
// the 2x2 layout; chip DS traffic -21%). A (16KB) + B (32KB) single 48KB
// buffer, R8's proven loop discipline: stage -> syncthreads -> compute ->
// syncthreads. XOR swizzle (128B rows) on both operands (rule #21: inverse on
// global source, same on ds_read). Swapped MFMA: D rows = h, D cols = m.
// Wave w owns n-cols [w*64, w*64+64) = exactly one channel.
__global__ __launch_bounds__(256, 2) void k_gemm_fused(
        const unsigned short* __restrict__ dataB,   // [4096][256] bf16
        const unsigned short* __restrict__ W2t,     // [16384][256] bf16
        const float* __restrict__ g2,               // [16384] 2*g
        const float* __restrict__ bi2,              // [16384] K2*b_in
        const float* __restrict__ BO,               // [256]  b_out + sum_h g
        float* __restrict__ out1)                   // [4096][256]
{
    __shared__ __align__(16) char lds[49152];       // A: [0,16K)  B: [16K,48K)
    const int tid  = threadIdx.x;
    const int w    = tid >> 6;
    const int lane = tid & 63;
    const int lq   = lane >> 4, lr = lane & 15;

    // Bijective XCD swizzle: 2048 blocks = 8 XCD x (8 n x 32 m).
    // Per XCD: B 8x256colsx512B = 1MB + A 2MB -> fits 4MB L2.
    const int orig = (int)blockIdx.x;
    const int swz  = (orig & 7) * 256 + (orig >> 3);
    const int bm0  = (swz & 31) << 7;               // 0..31 -> *128
    const int bn0  = (swz >> 5) << 8;               // 0..63 -> *256

    f4v acc[8][4];
#pragma unroll
    for (int mi = 0; mi < 8; ++mi)
#pragma unroll
        for (int ni = 0; ni < 4; ++ni)
            acc[mi][ni] = (f4v){0.f, 0.f, 0.f, 0.f};

    // Staging offsets. LDS dest LINEAR (global_load_lds constraint); XOR
    // swizzle on GLOBAL source + again on ds_read (rule #21).
    // A tile 16KB (4 rounds), B tile 32KB (8 rounds); 128B rows both.
    unsigned int offA[4], ldsoA[4], offB[8], ldsoB[8];
#pragma unroll
    for (int t = 0; t < 4; ++t) {
        int o = w * 4096 + t * 1024 + lane * 16;
        int row = o >> 7;
        int inner = (o & 127) ^ ((row & 7) << 4);
        ldsoA[t] = (unsigned)(w * 4096 + t * 1024);
        offA[t]  = (unsigned)(bm0 + row) * 512u + (unsigned)inner;
    }
#pragma unroll
    for (int t = 0; t < 8; ++t) {
        int o = w * 8192 + t * 1024 + lane * 16;
        int row = o >> 7;
        int inner = (o & 127) ^ ((row & 7) << 4);
        ldsoB[t] = (unsigned)(16384 + w * 8192 + t * 1024);
        offB[t]  = (unsigned)(bn0 + row) * 512u + (unsigned)inner;
    }

    const char* dA = (const char*)dataB;
    const char* dB = (const char*)W2t;

    for (int kt = 0; kt < 4; ++kt) {
#pragma unroll
        for (int t = 0; t < 4; ++t)
            gload16(dA + (size_t)offA[t] + kt * 128, lds + ldsoA[t]);
#pragma unroll
        for (int t = 0; t < 8; ++t)
            gload16(dB + (size_t)offB[t] + kt * 128, lds + ldsoB[t]);
        __syncthreads();   // compiler drains vmcnt before s_barrier

#pragma unroll
        for (int kk = 0; kk < 2; ++kk) {
            s8v afr[8], bfr[4];
#pragma unroll
            for (int mi = 0; mi < 8; ++mi) {
                int ml = mi * 16 + lr;               // wave reads ALL 128 A-rows
                int inner = (kk * 64 + (lq << 4)) ^ ((ml & 7) << 4);
                afr[mi] = *reinterpret_cast<const s8v*>(lds + ml * 128 + inner);
            }
#pragma unroll
            for (int ni = 0; ni < 4; ++ni) {
                int nl = w * 64 + ni * 16 + lr;      // wave-private n-slice
                int inner = (kk * 64 + (lq << 4)) ^ ((nl & 7) << 4);
                bfr[ni] = *reinterpret_cast<const s8v*>(lds + 16384 + nl * 128 + inner);
            }
            __builtin_amdgcn_s_setprio(1);
#pragma unroll
            for (int mi = 0; mi < 8; ++mi)
#pragma unroll
                for (int ni = 0; ni < 4; ++ni)
                    acc[mi][ni] = __builtin_amdgcn_mfma_f32_16x16x32_bf16(
                        bfr[ni], afr[mi], acc[mi][ni], 0, 0, 0);   // SWAPPED: W first
            __builtin_amdgcn_s_setprio(0);
        }
        __syncthreads();
    }

    // Epilogue (R8-validated layout): lane holds D[h = ni*16+lq*4+j][m = lr].
    // out[m,c] = BO[c] - sum_h g2[h] * rcp(1 + exp2(K2*pre + bi2[h]))
    const int cidx = (bn0 >> 6) + w;                // this wave's channel c
    float4 g2v[4], bi2v[4];
#pragma unroll
    for (int ni = 0; ni < 4; ++ni) {
        int base = cidx * 64 + ni * 16 + lq * 4;
        g2v[ni]  = *(const float4*)&g2 [base];
        bi2v[ni] = *(const float4*)&bi2[base];
    }
    const float BOv = BO[cidx];

    float s0, s1, s2, s3, s4, s5, s6, s7;
#define EPI_TERM(T, GC, BC, RR)                                                \
    { float mm = __builtin_fmaf(acc[mi][ni][RR], K2F, (BC));                   \
      float e  = __builtin_amdgcn_exp2f(mm);                                   \
      (T) = __builtin_fmaf((GC), __builtin_amdgcn_rcpf(e + 1.0f), (T)); }
#define EPI_MI(T, MI)                                                          \
    { const int mi = (MI); float t = 0.f;                                      \
      _Pragma("unroll")                                                        \
      for (int ni = 0; ni < 4; ++ni) {                                         \
          EPI_TERM(t, g2v[ni].x, bi2v[ni].x, 0);                               \
          EPI_TERM(t, g2v[ni].y, bi2v[ni].y, 1);                               \
          EPI_TERM(t, g2v[ni].z, bi2v[ni].z, 2);                               \
          EPI_TERM(t, g2v[ni].w, bi2v[ni].w, 3);                               \
      }                                                                        \
      t += __shfl_xor(t, 16);                                                  \
      t += __shfl_xor(t, 32);                                                  \
      (T) = t; }
    EPI_MI(s0, 0); EPI_MI(s1, 1); EPI_MI(s2, 2); EPI_MI(s3, 3);
    EPI_MI(s4, 4); EPI_MI(s5, 5); EPI_MI(s6, 6); EPI_MI(s7, 7);
#undef EPI_MI
#undef EPI_TERM
    // Wave writes 128 rows x 1 col: rows 0-63 from s0..s3, 64-127 from s4..s7.
    float vlo = lane < 16 ? s0 : (lane < 32 ? s1 : (lane < 48 ? s2 : s3));
    float vhi = lane < 16 ? s4 : (lane < 32 ? s5 : (lane < 48 ? s6 : s7));
    out1[(unsigned)(bm0 + lane) * NV + cidx]      = BOv - vlo;
    out1[(unsigned)(bm0 + 64 + lane) * NV + cidx] = BOv - vhi;
}

extern "C" void kernel_launch(void* const* d_in, const int* in_sizes, int n_in,
                              void* d_out, int out_size, void* d_ws, size_t ws_size,
                              hipStream_t stream) {
    const float* data    = (const float*)d_in[0];
    const float* adj     = (const float*)d_in[1];
    const float* neurons = (const float*)d_in[2];
    const float* w_in    = (const float*)d_in[3];
    const float* b_in    = (const float*)d_in[4];
    const float* w_out   = (const float*)d_in[5];
    const float* b_out   = (const float*)d_in[6];

    float* out0 = (float*)d_out;
    float* out1 = out0 + NV * NV;

    unsigned short* dataB = (unsigned short*)d_ws;                       // 2 MiB
    unsigned short* W2t   = (unsigned short*)((char*)d_ws + 2097152);    // 8 MiB
    float*          g2    = (float*)((char*)d_ws + 10485760);            // 64 KiB
    float*          bi2   = (float*)((char*)d_ws + 10551296);            // 64 KiB
    float*          BO    = (float*)((char*)d_ws + 10616832);            // 1 KiB

    hipLaunchKernelGGL(k_prep_all, dim3(2192), dim3(256), 0, stream,
                       adj, w_in, W2t, data, dataB, out0,
                       neurons, w_out, b_out, g2, BO, b_in, bi2);
    hipLaunchKernelGGL(k_gemm_fused, dim3(2048), dim3(256), 0, stream,
                       dataB, W2t, g2, bi2, BO, out1);
}